// Round 1
// baseline (1567.139 us; speedup 1.0000x reference)
//
#include <hip/hip_runtime.h>
#include <hip/hip_bf16.h>
#include <math.h>

#define N_TOK 8192
#define DIM   1024
#define NEXP  8
#define FDIM  2752
#define BK    32
#define LDSS  40            // BK + 8 pad (bf16 elems); 80 B row stride, 16B-aligned

typedef __bf16 v8bf __attribute__((ext_vector_type(8)));
typedef float  v4f  __attribute__((ext_vector_type(4)));

// ws layout (bytes)
#define WS_HDR     0        // int[64]: [0..7]=counts, [8..15]=cursor, [16..24]=poff(poff[8]=total), [25]=unused
#define WS_LOADSUM 256      // float[8]
#define WS_IDS     512      // int[2*N_TOK]
#define WS_PROBS   66048    // float[2*N_TOK]
#define WS_PERM    131584   // int[17408]
#define WS_WGT     201216   // float[17408]
#define WS_H       270848   // bf16[17408 * FDIM]  (~95.8 MB)

// ---------------- gating: logits -> softmax -> top2 -> renorm ----------------
__global__ __launch_bounds__(256) void gate_kernel(
    const float* __restrict__ x, const float* __restrict__ gw,
    int* __restrict__ hdr, float* __restrict__ load_sum,
    int* __restrict__ ids, float* __restrict__ probs)
{
    __shared__ float s_load[NEXP];
    __shared__ int   s_cnt[NEXP];
    int tid = threadIdx.x;
    if (tid < NEXP) { s_load[tid] = 0.f; s_cnt[tid] = 0; }
    __syncthreads();

    int wave = tid >> 6, lane = tid & 63;
    int tok = blockIdx.x * 4 + wave;
    float acc[NEXP];
#pragma unroll
    for (int e = 0; e < NEXP; e++) acc[e] = 0.f;
    const float* xr = x + (size_t)tok * DIM;
    for (int d = lane; d < DIM; d += 64) {
        float xv = xr[d];
#pragma unroll
        for (int e = 0; e < NEXP; e++) acc[e] = fmaf(xv, gw[d * NEXP + e], acc[e]);
    }
#pragma unroll
    for (int e = 0; e < NEXP; e++) {
#pragma unroll
        for (int off = 32; off > 0; off >>= 1) acc[e] += __shfl_xor(acc[e], off, 64);
    }
    if (lane == 0) {
        float m = acc[0];
#pragma unroll
        for (int e = 1; e < NEXP; e++) m = fmaxf(m, acc[e]);
        float p[NEXP], s = 0.f;
#pragma unroll
        for (int e = 0; e < NEXP; e++) { p[e] = __expf(acc[e] - m); s += p[e]; }
        float inv = 1.f / s;
#pragma unroll
        for (int e = 0; e < NEXP; e++) p[e] *= inv;
        int i1 = 0; float p1 = p[0];
#pragma unroll
        for (int e = 1; e < NEXP; e++) if (p[e] > p1) { p1 = p[e]; i1 = e; }
        int i2 = -1; float p2 = -1.f;
#pragma unroll
        for (int e = 0; e < NEXP; e++) if (e != i1 && p[e] > p2) { p2 = p[e]; i2 = e; }
        float rs = 1.f / (p1 + p2 + 1e-8f);
        ids[tok * 2] = i1;  ids[tok * 2 + 1] = i2;
        probs[tok * 2] = p1 * rs;  probs[tok * 2 + 1] = p2 * rs;
#pragma unroll
        for (int e = 0; e < NEXP; e++) atomicAdd(&s_load[e], p[e]);
        atomicAdd(&s_cnt[i1], 1);  atomicAdd(&s_cnt[i2], 1);
    }
    __syncthreads();
    if (tid < NEXP) {
        atomicAdd(&load_sum[tid], s_load[tid]);
        atomicAdd(&hdr[tid], s_cnt[tid]);
    }
}

// ---------------- scan: 64-aligned segment offsets + aux loss ----------------
__global__ void scan_kernel(int* __restrict__ hdr, const float* __restrict__ load_sum,
                            float* __restrict__ aux_out)
{
    if (threadIdx.x == 0) {
        int off = 0;
        float aux = 0.f;
        for (int e = 0; e < NEXP; e++) {
            hdr[16 + e] = off;
            int c = hdr[e];
            off += (c + 63) & ~63;
            aux += ((float)c / (float)(N_TOK * 2)) * (load_sum[e] / (float)N_TOK);
        }
        hdr[24] = off;   // total padded rows
        *aux_out = 0.01f * 8.f * aux;
    }
}

// ---------------- scatter: build per-expert token lists ----------------
__global__ __launch_bounds__(256) void scatter_kernel(
    const int* __restrict__ ids, const float* __restrict__ probs,
    int* __restrict__ hdr, int* __restrict__ perm, float* __restrict__ wgt)
{
    int t = blockIdx.x * 256 + threadIdx.x;
#pragma unroll
    for (int k = 0; k < 2; k++) {
        int e = ids[t * 2 + k];
        int pos = atomicAdd(&hdr[8 + e], 1);
        int slot = hdr[16 + e] + pos;
        perm[slot] = t;
        wgt[slot] = probs[t * 2 + k];
    }
}

// ---------------- pass A: H = silu(X@Wg) * (X@Wu), grouped by expert ----------------
__global__ __launch_bounds__(256) void gemm_a(
    const float* __restrict__ x, const float* __restrict__ w_gate,
    const float* __restrict__ w_up, const int* __restrict__ hdr,
    const int* __restrict__ perm, __bf16* __restrict__ Hb)
{
    int mtile = blockIdx.y, ftile = blockIdx.x;
    int mbase = mtile * 64;
    if (mbase >= hdr[24]) return;
    int e = 0;
    while (mbase >= hdr[17 + e]) e++;     // poff[e] <= mbase < poff[e+1]; poff[8]=total
    const float* wg = w_gate + (size_t)e * DIM * FDIM;
    const float* wu = w_up   + (size_t)e * DIM * FDIM;
    int fbase = ftile * 64;

    __shared__ __align__(16) __bf16 sA[64 * LDSS];
    __shared__ __align__(16) __bf16 sBg[64 * LDSS];
    __shared__ __align__(16) __bf16 sBu[64 * LDSS];

    int tid = threadIdx.x;
    int ar = tid >> 2, ac = (tid & 3) * 8;       // A staging: row, col8
    int bn = tid & 63, bk = (tid >> 6) * 8;      // B staging: col(n), k8
    int wave = tid >> 6, lane = tid & 63;
    int wm = (wave >> 1) * 32, wn = (wave & 1) * 32;
    int fm = lane & 15, fk = (lane >> 4) * 8;

    int tok = perm[mbase + ar];
    const float* xrow = x + (size_t)tok * DIM;

    v4f accg[2][2], accu[2][2];
#pragma unroll
    for (int i = 0; i < 2; i++)
#pragma unroll
        for (int j = 0; j < 2; j++) {
            accg[i][j] = (v4f){0.f, 0.f, 0.f, 0.f};
            accu[i][j] = (v4f){0.f, 0.f, 0.f, 0.f};
        }

    for (int k0 = 0; k0 < DIM; k0 += BK) {
        float4 a0 = *(const float4*)(xrow + k0 + ac);
        float4 a1 = *(const float4*)(xrow + k0 + ac + 4);
        v8bf va;
        va[0] = (__bf16)a0.x; va[1] = (__bf16)a0.y; va[2] = (__bf16)a0.z; va[3] = (__bf16)a0.w;
        va[4] = (__bf16)a1.x; va[5] = (__bf16)a1.y; va[6] = (__bf16)a1.z; va[7] = (__bf16)a1.w;
        *(v8bf*)&sA[ar * LDSS + ac] = va;

        v8bf vg, vu;
#pragma unroll
        for (int j = 0; j < 8; j++) {
            size_t gi = (size_t)(k0 + bk + j) * FDIM + fbase + bn;
            vg[j] = (__bf16)wg[gi];
            vu[j] = (__bf16)wu[gi];
        }
        *(v8bf*)&sBg[bn * LDSS + bk] = vg;
        *(v8bf*)&sBu[bn * LDSS + bk] = vu;
        __syncthreads();

        v8bf af[2], bg[2], bu[2];
#pragma unroll
        for (int i = 0; i < 2; i++) af[i] = *(v8bf*)&sA[(wm + i * 16 + fm) * LDSS + fk];
#pragma unroll
        for (int j = 0; j < 2; j++) {
            bg[j] = *(v8bf*)&sBg[(wn + j * 16 + fm) * LDSS + fk];
            bu[j] = *(v8bf*)&sBu[(wn + j * 16 + fm) * LDSS + fk];
        }
#pragma unroll
        for (int i = 0; i < 2; i++)
#pragma unroll
            for (int j = 0; j < 2; j++) {
                accg[i][j] = __builtin_amdgcn_mfma_f32_16x16x32_bf16(af[i], bg[j], accg[i][j], 0, 0, 0);
                accu[i][j] = __builtin_amdgcn_mfma_f32_16x16x32_bf16(af[i], bu[j], accu[i][j], 0, 0, 0);
            }
        __syncthreads();
    }

    // epilogue: h = silu(g) * u  -> bf16 H
    int rq = (lane >> 4) * 4;
#pragma unroll
    for (int i = 0; i < 2; i++)
#pragma unroll
        for (int j = 0; j < 2; j++)
#pragma unroll
            for (int r = 0; r < 4; r++) {
                float g = accg[i][j][r], u = accu[i][j][r];
                float h = g / (1.f + __expf(-g)) * u;
                int row = mbase + wm + i * 16 + rq + r;
                int col = fbase + wn + j * 16 + fm;
                Hb[(size_t)row * FDIM + col] = (__bf16)h;
            }
}

// ---------------- pass B: out += w * (H @ Wd), grouped by expert ----------------
__global__ __launch_bounds__(256) void gemm_b(
    const __bf16* __restrict__ Hb, const float* __restrict__ w_down,
    const int* __restrict__ hdr, const int* __restrict__ perm,
    const float* __restrict__ wgt, float* __restrict__ out)
{
    int mtile = blockIdx.y, ntile = blockIdx.x;
    int mbase = mtile * 64;
    if (mbase >= hdr[24]) return;
    int e = 0;
    while (mbase >= hdr[17 + e]) e++;
    const float* wd = w_down + (size_t)e * FDIM * DIM;
    int nbase = ntile * 64;

    __shared__ __align__(16) __bf16 sA[64 * LDSS];
    __shared__ __align__(16) __bf16 sB[64 * LDSS];

    int tid = threadIdx.x;
    int ar = tid >> 2, ac = (tid & 3) * 8;
    int bn = tid & 63, bk = (tid >> 6) * 8;
    int wave = tid >> 6, lane = tid & 63;
    int wm = (wave >> 1) * 32, wn = (wave & 1) * 32;
    int fm = lane & 15, fk = (lane >> 4) * 8;

    const __bf16* hrow = Hb + (size_t)(mbase + ar) * FDIM;

    v4f acc[2][2];
#pragma unroll
    for (int i = 0; i < 2; i++)
#pragma unroll
        for (int j = 0; j < 2; j++) acc[i][j] = (v4f){0.f, 0.f, 0.f, 0.f};

    for (int k0 = 0; k0 < FDIM; k0 += BK) {
        *(v8bf*)&sA[ar * LDSS + ac] = *(const v8bf*)(hrow + k0 + ac);
        v8bf vb;
#pragma unroll
        for (int j = 0; j < 8; j++)
            vb[j] = (__bf16)wd[(size_t)(k0 + bk + j) * DIM + nbase + bn];
        *(v8bf*)&sB[bn * LDSS + bk] = vb;
        __syncthreads();

        v8bf af[2], bf[2];
#pragma unroll
        for (int i = 0; i < 2; i++) af[i] = *(v8bf*)&sA[(wm + i * 16 + fm) * LDSS + fk];
#pragma unroll
        for (int j = 0; j < 2; j++) bf[j] = *(v8bf*)&sB[(wn + j * 16 + fm) * LDSS + fk];
#pragma unroll
        for (int i = 0; i < 2; i++)
#pragma unroll
            for (int j = 0; j < 2; j++)
                acc[i][j] = __builtin_amdgcn_mfma_f32_16x16x32_bf16(af[i], bf[j], acc[i][j], 0, 0, 0);
        __syncthreads();
    }

    int rq = (lane >> 4) * 4;
#pragma unroll
    for (int i = 0; i < 2; i++)
#pragma unroll
        for (int r = 0; r < 4; r++) {
            int row = mbase + wm + i * 16 + rq + r;
            float w = wgt[row];
            int tok = perm[row];
            size_t ob = (size_t)tok * DIM + nbase + wn + fm;
            atomicAdd(&out[ob],      acc[i][0][r] * w);
            atomicAdd(&out[ob + 16], acc[i][1][r] * w);
        }
}

extern "C" void kernel_launch(void* const* d_in, const int* in_sizes, int n_in,
                              void* d_out, int out_size, void* d_ws, size_t ws_size,
                              hipStream_t stream)
{
    const float* x      = (const float*)d_in[0];
    const float* gate_w = (const float*)d_in[1];
    const float* w_gate = (const float*)d_in[2];
    const float* w_up   = (const float*)d_in[3];
    const float* w_down = (const float*)d_in[4];
    float* out = (float*)d_out;

    char* ws = (char*)d_ws;
    int*   hdr      = (int*)(ws + WS_HDR);
    float* load_sum = (float*)(ws + WS_LOADSUM);
    int*   ids      = (int*)(ws + WS_IDS);
    float* probs    = (float*)(ws + WS_PROBS);
    int*   perm     = (int*)(ws + WS_PERM);
    float* wgt      = (float*)(ws + WS_WGT);
    __bf16* Hb      = (__bf16*)(ws + WS_H);

    hipMemsetAsync(ws, 0, 512, stream);                       // hdr + load_sum
    hipMemsetAsync(ws + WS_PERM, 0, 2 * 17408 * 4, stream);   // perm + wgt (pads -> tok 0, w 0)
    hipMemsetAsync(d_out, 0, (size_t)out_size * sizeof(float), stream);

    gate_kernel<<<N_TOK / 4, 256, 0, stream>>>(x, gate_w, hdr, load_sum, ids, probs);
    scan_kernel<<<1, 64, 0, stream>>>(hdr, load_sum, out + (size_t)N_TOK * DIM);
    scatter_kernel<<<N_TOK / 256, 256, 0, stream>>>(ids, probs, hdr, perm, wgt);
    gemm_a<<<dim3(FDIM / 64, 264), 256, 0, stream>>>(x, w_gate, w_up, hdr, perm, Hb);
    gemm_b<<<dim3(DIM / 64, 264), 256, 0, stream>>>(Hb, w_down, hdr, perm, wgt, out);
}

// Round 2
// 916.451 us; speedup vs baseline: 1.7100x; 1.7100x over previous
//
#include <hip/hip_runtime.h>
#include <hip/hip_bf16.h>
#include <math.h>

#define N_TOK 8192
#define DIM   1024
#define NEXP  8
#define FDIM  2752
#define BK    32
#define MT    128
#define NT    128
#define LDSS  40            // fallback kernels: BK + 8 pad

typedef __bf16 v8bf __attribute__((ext_vector_type(8)));
typedef float  v4f  __attribute__((ext_vector_type(4)));

// ws layout (bytes)
#define WS_HDR     0                // int[64]: [0..7]=counts [8..15]=cursor [16..24]=poff (poff[8]=total)
#define WS_LOADSUM 256              // float[8]
#define WS_IDS     512              // int[2*N_TOK]
#define WS_PROBS   66048            // float[2*N_TOK]
#define WS_PERM    131584           // int[17408]
#define WS_WGT     201216           // float[17408]
#define WS_H       270848           // bf16[17408*FDIM] = 95,813,632 B
#define WS_XBF     96084480ull      // bf16[N_TOK*DIM] = 16,777,216 B
#define WS_WG_T    112861696ull     // bf16[8*FDIM*DIM] = 45,088,768 B each
#define WS_WU_T    157950464ull
#define WS_WD_T    203039232ull
#define WS_NEED    248128512ull

__device__ __forceinline__ void gld16(const __bf16* g, __bf16* l) {
    __builtin_amdgcn_global_load_lds(
        (const __attribute__((address_space(1))) void*)g,
        (__attribute__((address_space(3))) void*)l, 16, 0, 0);
}

// ---------------- gating: logits -> softmax -> top2 -> renorm (+ x cast) ----------------
__global__ __launch_bounds__(256) void gate_kernel(
    const float* __restrict__ x, const float* __restrict__ gw,
    int* __restrict__ hdr, float* __restrict__ load_sum,
    int* __restrict__ ids, float* __restrict__ probs, __bf16* __restrict__ xb)
{
    __shared__ float s_load[NEXP];
    __shared__ int   s_cnt[NEXP];
    int tid = threadIdx.x;
    if (tid < NEXP) { s_load[tid] = 0.f; s_cnt[tid] = 0; }
    __syncthreads();

    int wave = tid >> 6, lane = tid & 63;
    int tok = blockIdx.x * 4 + wave;
    float acc[NEXP];
#pragma unroll
    for (int e = 0; e < NEXP; e++) acc[e] = 0.f;
    const float* xr = x + (size_t)tok * DIM;
    for (int d = lane; d < DIM; d += 64) {
        float xv = xr[d];
        if (xb) xb[(size_t)tok * DIM + d] = (__bf16)xv;
#pragma unroll
        for (int e = 0; e < NEXP; e++) acc[e] = fmaf(xv, gw[d * NEXP + e], acc[e]);
    }
#pragma unroll
    for (int e = 0; e < NEXP; e++) {
#pragma unroll
        for (int off = 32; off > 0; off >>= 1) acc[e] += __shfl_xor(acc[e], off, 64);
    }
    if (lane == 0) {
        float m = acc[0];
#pragma unroll
        for (int e = 1; e < NEXP; e++) m = fmaxf(m, acc[e]);
        float p[NEXP], s = 0.f;
#pragma unroll
        for (int e = 0; e < NEXP; e++) { p[e] = __expf(acc[e] - m); s += p[e]; }
        float inv = 1.f / s;
#pragma unroll
        for (int e = 0; e < NEXP; e++) p[e] *= inv;
        int i1 = 0; float p1 = p[0];
#pragma unroll
        for (int e = 1; e < NEXP; e++) if (p[e] > p1) { p1 = p[e]; i1 = e; }
        int i2 = -1; float p2 = -1.f;
#pragma unroll
        for (int e = 0; e < NEXP; e++) if (e != i1 && p[e] > p2) { p2 = p[e]; i2 = e; }
        float rs = 1.f / (p1 + p2 + 1e-8f);
        ids[tok * 2] = i1;  ids[tok * 2 + 1] = i2;
        probs[tok * 2] = p1 * rs;  probs[tok * 2 + 1] = p2 * rs;
#pragma unroll
        for (int e = 0; e < NEXP; e++) atomicAdd(&s_load[e], p[e]);
        atomicAdd(&s_cnt[i1], 1);  atomicAdd(&s_cnt[i2], 1);
    }
    __syncthreads();
    if (tid < NEXP) {
        atomicAdd(&load_sum[tid], s_load[tid]);
        atomicAdd(&hdr[tid], s_cnt[tid]);
    }
}

// ---------------- scan: 128-aligned segment offsets + aux loss ----------------
__global__ void scan_kernel(int* __restrict__ hdr, const float* __restrict__ load_sum,
                            float* __restrict__ aux_out)
{
    if (threadIdx.x == 0) {
        int off = 0;
        float aux = 0.f;
        for (int e = 0; e < NEXP; e++) {
            hdr[16 + e] = off;
            int c = hdr[e];
            off += (c + 127) & ~127;
            aux += ((float)c / (float)(N_TOK * 2)) * (load_sum[e] / (float)N_TOK);
        }
        hdr[24] = off;
        *aux_out = 0.01f * 8.f * aux;
    }
}

// ---------------- scatter ----------------
__global__ __launch_bounds__(256) void scatter_kernel(
    const int* __restrict__ ids, const float* __restrict__ probs,
    int* __restrict__ hdr, int* __restrict__ perm, float* __restrict__ wgt)
{
    int t = blockIdx.x * 256 + threadIdx.x;
#pragma unroll
    for (int k = 0; k < 2; k++) {
        int e = ids[t * 2 + k];
        int pos = atomicAdd(&hdr[8 + e], 1);
        int slot = hdr[16 + e] + pos;
        perm[slot] = t;
        wgt[slot] = probs[t * 2 + k];
    }
}

// ---------------- transpose+cast: src [R][C] f32 -> dst [C][R] bf16 (per slab z) ----------------
__global__ __launch_bounds__(256) void transpose_cast(
    const float* __restrict__ src, __bf16* __restrict__ dst, int R, int C)
{
    __shared__ float tile[64][65];
    size_t slab = (size_t)blockIdx.z * (size_t)R * C;
    const float* s = src + slab;
    __bf16* d = dst + slab;
    int cb = blockIdx.x * 64, rb = blockIdx.y * 64;
    int tid = threadIdx.x;
    int c = tid & 63;
#pragma unroll
    for (int p = 0; p < 16; p++) {
        int r = p * 4 + (tid >> 6);
        tile[r][c] = s[(size_t)(rb + r) * C + cb + c];
    }
    __syncthreads();
#pragma unroll
    for (int p = 0; p < 2; p++) {
        int cc = p * 32 + (tid >> 3);
        int rr0 = (tid & 7) * 8;
        v8bf v;
#pragma unroll
        for (int j = 0; j < 8; j++) v[j] = (__bf16)tile[rr0 + j][cc];
        *(v8bf*)&d[(size_t)(cb + cc) * R + rb + rr0] = v;
    }
}

// ---------------- pass A: H = silu(X@Wg)*(X@Wu), 128x128 tiles, bf16 weights ----------------
__global__ __launch_bounds__(256, 2) void gemm_a(
    const __bf16* __restrict__ xb, const __bf16* __restrict__ wg_t,
    const __bf16* __restrict__ wu_t, const int* __restrict__ hdr,
    const int* __restrict__ perm, __bf16* __restrict__ Hb)
{
    int mbase = blockIdx.y * MT;
    if (mbase >= hdr[24]) return;
    int e = 0;
    while (mbase >= hdr[17 + e]) e++;
    const __bf16* wg = wg_t + (size_t)e * DIM * FDIM;   // [F][K]
    const __bf16* wu = wu_t + (size_t)e * DIM * FDIM;
    int fbase = blockIdx.x * NT;

    __shared__ __align__(16) __bf16 sA[MT * BK];
    __shared__ __align__(16) __bf16 sBg[NT * BK];
    __shared__ __align__(16) __bf16 sBu[NT * BK];

    int tid = threadIdx.x, wave = tid >> 6, lane = tid & 63;
    int srow = wave * 32 + (lane >> 2);     // staging row (first of pair)
    int scole = (lane & 3) * 8;             // k-elem offset within row

    int prow0 = perm[mbase + srow];
    int prow1 = perm[mbase + srow + 16];
    const __bf16* ag0 = xb + (size_t)prow0 * DIM + scole;
    const __bf16* ag1 = xb + (size_t)prow1 * DIM + scole;
    const __bf16* bg0 = wg + (size_t)(fbase + srow) * DIM + scole;
    const __bf16* bg1 = wg + (size_t)(fbase + srow + 16) * DIM + scole;
    const __bf16* bu0 = wu + (size_t)(fbase + srow) * DIM + scole;
    const __bf16* bu1 = wu + (size_t)(fbase + srow + 16) * DIM + scole;

    __bf16* lA0 = sA  + (wave * 32) * BK;
    __bf16* lA1 = sA  + (wave * 32 + 16) * BK;
    __bf16* lG0 = sBg + (wave * 32) * BK;
    __bf16* lG1 = sBg + (wave * 32 + 16) * BK;
    __bf16* lU0 = sBu + (wave * 32) * BK;
    __bf16* lU1 = sBu + (wave * 32 + 16) * BK;

    int wm = (wave >> 1) * 64, wn = (wave & 1) * 64;
    int fm = lane & 15, fko = (lane >> 4) * 8;

    v4f accg[4][4], accu[4][4];
#pragma unroll
    for (int i = 0; i < 4; i++)
#pragma unroll
        for (int j = 0; j < 4; j++) {
            accg[i][j] = (v4f){0.f, 0.f, 0.f, 0.f};
            accu[i][j] = (v4f){0.f, 0.f, 0.f, 0.f};
        }

    for (int k0 = 0; k0 < DIM; k0 += BK) {
        gld16(ag0, lA0);  gld16(ag1, lA1);
        gld16(bg0, lG0);  gld16(bg1, lG1);
        gld16(bu0, lU0);  gld16(bu1, lU1);
        ag0 += BK; ag1 += BK; bg0 += BK; bg1 += BK; bu0 += BK; bu1 += BK;
        __syncthreads();

        v8bf af[4], bgf[4], buf_[4];
#pragma unroll
        for (int i = 0; i < 4; i++) af[i] = *(v8bf*)&sA[(wm + i * 16 + fm) * BK + fko];
#pragma unroll
        for (int j = 0; j < 4; j++) {
            bgf[j]  = *(v8bf*)&sBg[(wn + j * 16 + fm) * BK + fko];
            buf_[j] = *(v8bf*)&sBu[(wn + j * 16 + fm) * BK + fko];
        }
#pragma unroll
        for (int i = 0; i < 4; i++)
#pragma unroll
            for (int j = 0; j < 4; j++) {
                accg[i][j] = __builtin_amdgcn_mfma_f32_16x16x32_bf16(af[i], bgf[j],  accg[i][j], 0, 0, 0);
                accu[i][j] = __builtin_amdgcn_mfma_f32_16x16x32_bf16(af[i], buf_[j], accu[i][j], 0, 0, 0);
            }
        __syncthreads();
    }

    int rq = (lane >> 4) * 4;
#pragma unroll
    for (int i = 0; i < 4; i++) {
        int row = mbase + wm + i * 16 + rq;
#pragma unroll
        for (int j = 0; j < 4; j++) {
            int col = fbase + wn + j * 16 + fm;
            if (col < FDIM) {
#pragma unroll
                for (int r = 0; r < 4; r++) {
                    float g = accg[i][j][r], u = accu[i][j][r];
                    float h = g / (1.f + __expf(-g)) * u;
                    Hb[(size_t)(row + r) * FDIM + col] = (__bf16)h;
                }
            }
        }
    }
}

// ---------------- pass B: out += w * (H @ Wd), 128x128 tiles ----------------
__global__ __launch_bounds__(256, 2) void gemm_b(
    const __bf16* __restrict__ Hb, const __bf16* __restrict__ wd_t,
    const int* __restrict__ hdr, const int* __restrict__ perm,
    const float* __restrict__ wgt, float* __restrict__ out)
{
    int mbase = blockIdx.y * MT;
    if (mbase >= hdr[24]) return;
    int e = 0;
    while (mbase >= hdr[17 + e]) e++;
    const __bf16* wd = wd_t + (size_t)e * FDIM * DIM;   // [D][F]
    int nbase = blockIdx.x * NT;

    __shared__ __align__(16) __bf16 sA[MT * BK];
    __shared__ __align__(16) __bf16 sB[NT * BK];

    int tid = threadIdx.x, wave = tid >> 6, lane = tid & 63;
    int srow = wave * 32 + (lane >> 2);
    int scole = (lane & 3) * 8;

    const __bf16* ag0 = Hb + (size_t)(mbase + srow) * FDIM + scole;
    const __bf16* ag1 = Hb + (size_t)(mbase + srow + 16) * FDIM + scole;
    const __bf16* bg0 = wd + (size_t)(nbase + srow) * FDIM + scole;
    const __bf16* bg1 = wd + (size_t)(nbase + srow + 16) * FDIM + scole;

    __bf16* lA0 = sA + (wave * 32) * BK;
    __bf16* lA1 = sA + (wave * 32 + 16) * BK;
    __bf16* lB0 = sB + (wave * 32) * BK;
    __bf16* lB1 = sB + (wave * 32 + 16) * BK;

    int wm = (wave >> 1) * 64, wn = (wave & 1) * 64;
    int fm = lane & 15, fko = (lane >> 4) * 8;

    v4f acc[4][4];
#pragma unroll
    for (int i = 0; i < 4; i++)
#pragma unroll
        for (int j = 0; j < 4; j++) acc[i][j] = (v4f){0.f, 0.f, 0.f, 0.f};

    for (int k0 = 0; k0 < FDIM; k0 += BK) {
        gld16(ag0, lA0);  gld16(ag1, lA1);
        gld16(bg0, lB0);  gld16(bg1, lB1);
        ag0 += BK; ag1 += BK; bg0 += BK; bg1 += BK;
        __syncthreads();

        v8bf af[4], bf_[4];
#pragma unroll
        for (int i = 0; i < 4; i++) af[i]  = *(v8bf*)&sA[(wm + i * 16 + fm) * BK + fko];
#pragma unroll
        for (int j = 0; j < 4; j++) bf_[j] = *(v8bf*)&sB[(wn + j * 16 + fm) * BK + fko];
#pragma unroll
        for (int i = 0; i < 4; i++)
#pragma unroll
            for (int j = 0; j < 4; j++)
                acc[i][j] = __builtin_amdgcn_mfma_f32_16x16x32_bf16(af[i], bf_[j], acc[i][j], 0, 0, 0);
        __syncthreads();
    }

    int rq = (lane >> 4) * 4;
#pragma unroll
    for (int i = 0; i < 4; i++) {
#pragma unroll
        for (int r = 0; r < 4; r++) {
            int row = mbase + wm + i * 16 + rq + r;
            int tok = perm[row];
            float w = wgt[row];
            size_t ob = (size_t)tok * DIM + nbase + wn + fm;
#pragma unroll
            for (int j = 0; j < 4; j++)
                atomicAdd(&out[ob + j * 16], acc[i][j][r] * w);
        }
    }
}

// ================= fallback (round-1, fp32 weights on the fly) =================
__global__ __launch_bounds__(256) void gemm_a_f32(
    const float* __restrict__ x, const float* __restrict__ w_gate,
    const float* __restrict__ w_up, const int* __restrict__ hdr,
    const int* __restrict__ perm, __bf16* __restrict__ Hb)
{
    int mbase = blockIdx.y * 64;
    if (mbase >= hdr[24]) return;
    int e = 0;
    while (mbase >= hdr[17 + e]) e++;
    const float* wg = w_gate + (size_t)e * DIM * FDIM;
    const float* wu = w_up   + (size_t)e * DIM * FDIM;
    int fbase = blockIdx.x * 64;

    __shared__ __align__(16) __bf16 sA[64 * LDSS];
    __shared__ __align__(16) __bf16 sBg[64 * LDSS];
    __shared__ __align__(16) __bf16 sBu[64 * LDSS];

    int tid = threadIdx.x;
    int ar = tid >> 2, ac = (tid & 3) * 8;
    int bn = tid & 63, bk = (tid >> 6) * 8;
    int wave = tid >> 6, lane = tid & 63;
    int wm = (wave >> 1) * 32, wn = (wave & 1) * 32;
    int fm = lane & 15, fk = (lane >> 4) * 8;

    int tok = perm[mbase + ar];
    const float* xrow = x + (size_t)tok * DIM;

    v4f accg[2][2], accu[2][2];
#pragma unroll
    for (int i = 0; i < 2; i++)
#pragma unroll
        for (int j = 0; j < 2; j++) {
            accg[i][j] = (v4f){0.f, 0.f, 0.f, 0.f};
            accu[i][j] = (v4f){0.f, 0.f, 0.f, 0.f};
        }

    for (int k0 = 0; k0 < DIM; k0 += BK) {
        float4 a0 = *(const float4*)(xrow + k0 + ac);
        float4 a1 = *(const float4*)(xrow + k0 + ac + 4);
        v8bf va;
        va[0] = (__bf16)a0.x; va[1] = (__bf16)a0.y; va[2] = (__bf16)a0.z; va[3] = (__bf16)a0.w;
        va[4] = (__bf16)a1.x; va[5] = (__bf16)a1.y; va[6] = (__bf16)a1.z; va[7] = (__bf16)a1.w;
        *(v8bf*)&sA[ar * LDSS + ac] = va;
        v8bf vg, vu;
#pragma unroll
        for (int j = 0; j < 8; j++) {
            size_t gi = (size_t)(k0 + bk + j) * FDIM + fbase + bn;
            vg[j] = (__bf16)wg[gi];
            vu[j] = (__bf16)wu[gi];
        }
        *(v8bf*)&sBg[bn * LDSS + bk] = vg;
        *(v8bf*)&sBu[bn * LDSS + bk] = vu;
        __syncthreads();
        v8bf af[2], bg[2], bu[2];
#pragma unroll
        for (int i = 0; i < 2; i++) af[i] = *(v8bf*)&sA[(wm + i * 16 + fm) * LDSS + fk];
#pragma unroll
        for (int j = 0; j < 2; j++) {
            bg[j] = *(v8bf*)&sBg[(wn + j * 16 + fm) * LDSS + fk];
            bu[j] = *(v8bf*)&sBu[(wn + j * 16 + fm) * LDSS + fk];
        }
#pragma unroll
        for (int i = 0; i < 2; i++)
#pragma unroll
            for (int j = 0; j < 2; j++) {
                accg[i][j] = __builtin_amdgcn_mfma_f32_16x16x32_bf16(af[i], bg[j], accg[i][j], 0, 0, 0);
                accu[i][j] = __builtin_amdgcn_mfma_f32_16x16x32_bf16(af[i], bu[j], accu[i][j], 0, 0, 0);
            }
        __syncthreads();
    }

    int rq = (lane >> 4) * 4;
#pragma unroll
    for (int i = 0; i < 2; i++)
#pragma unroll
        for (int j = 0; j < 2; j++)
#pragma unroll
            for (int r = 0; r < 4; r++) {
                float g = accg[i][j][r], u = accu[i][j][r];
                float h = g / (1.f + __expf(-g)) * u;
                int row = mbase + wm + i * 16 + rq + r;
                int col = fbase + wn + j * 16 + fm;
                Hb[(size_t)row * FDIM + col] = (__bf16)h;
            }
}

__global__ __launch_bounds__(256) void gemm_b_f32(
    const __bf16* __restrict__ Hb, const float* __restrict__ w_down,
    const int* __restrict__ hdr, const int* __restrict__ perm,
    const float* __restrict__ wgt, float* __restrict__ out)
{
    int mbase = blockIdx.y * 64;
    if (mbase >= hdr[24]) return;
    int e = 0;
    while (mbase >= hdr[17 + e]) e++;
    const float* wd = w_down + (size_t)e * FDIM * DIM;
    int nbase = blockIdx.x * 64;

    __shared__ __align__(16) __bf16 sA[64 * LDSS];
    __shared__ __align__(16) __bf16 sB[64 * LDSS];

    int tid = threadIdx.x;
    int ar = tid >> 2, ac = (tid & 3) * 8;
    int bn = tid & 63, bk = (tid >> 6) * 8;
    int wave = tid >> 6, lane = tid & 63;
    int wm = (wave >> 1) * 32, wn = (wave & 1) * 32;
    int fm = lane & 15, fk = (lane >> 4) * 8;

    const __bf16* hrow = Hb + (size_t)(mbase + ar) * FDIM;

    v4f acc[2][2];
#pragma unroll
    for (int i = 0; i < 2; i++)
#pragma unroll
        for (int j = 0; j < 2; j++) acc[i][j] = (v4f){0.f, 0.f, 0.f, 0.f};

    for (int k0 = 0; k0 < FDIM; k0 += BK) {
        *(v8bf*)&sA[ar * LDSS + ac] = *(const v8bf*)(hrow + k0 + ac);
        v8bf vb;
#pragma unroll
        for (int j = 0; j < 8; j++)
            vb[j] = (__bf16)wd[(size_t)(k0 + bk + j) * DIM + nbase + bn];
        *(v8bf*)&sB[bn * LDSS + bk] = vb;
        __syncthreads();
        v8bf af[2], bf[2];
#pragma unroll
        for (int i = 0; i < 2; i++) af[i] = *(v8bf*)&sA[(wm + i * 16 + fm) * LDSS + fk];
#pragma unroll
        for (int j = 0; j < 2; j++) bf[j] = *(v8bf*)&sB[(wn + j * 16 + fm) * LDSS + fk];
#pragma unroll
        for (int i = 0; i < 2; i++)
#pragma unroll
            for (int j = 0; j < 2; j++)
                acc[i][j] = __builtin_amdgcn_mfma_f32_16x16x32_bf16(af[i], bf[j], acc[i][j], 0, 0, 0);
        __syncthreads();
    }

    int rq = (lane >> 4) * 4;
#pragma unroll
    for (int i = 0; i < 2; i++)
#pragma unroll
        for (int r = 0; r < 4; r++) {
            int row = mbase + wm + i * 16 + rq + r;
            float w = wgt[row];
            int tok = perm[row];
            size_t ob = (size_t)tok * DIM + nbase + wn + fm;
            atomicAdd(&out[ob],      acc[i][0][r] * w);
            atomicAdd(&out[ob + 16], acc[i][1][r] * w);
        }
}

extern "C" void kernel_launch(void* const* d_in, const int* in_sizes, int n_in,
                              void* d_out, int out_size, void* d_ws, size_t ws_size,
                              hipStream_t stream)
{
    const float* x      = (const float*)d_in[0];
    const float* gate_w = (const float*)d_in[1];
    const float* w_gate = (const float*)d_in[2];
    const float* w_up   = (const float*)d_in[3];
    const float* w_down = (const float*)d_in[4];
    float* out = (float*)d_out;

    char* ws = (char*)d_ws;
    int*   hdr      = (int*)(ws + WS_HDR);
    float* load_sum = (float*)(ws + WS_LOADSUM);
    int*   ids      = (int*)(ws + WS_IDS);
    float* probs    = (float*)(ws + WS_PROBS);
    int*   perm     = (int*)(ws + WS_PERM);
    float* wgt      = (float*)(ws + WS_WGT);
    __bf16* Hb      = (__bf16*)(ws + WS_H);

    bool fast = ws_size >= WS_NEED;
    __bf16* xb   = fast ? (__bf16*)(ws + WS_XBF)  : nullptr;
    __bf16* wg_t = (__bf16*)(ws + WS_WG_T);
    __bf16* wu_t = (__bf16*)(ws + WS_WU_T);
    __bf16* wd_t = (__bf16*)(ws + WS_WD_T);

    hipMemsetAsync(ws, 0, 512, stream);
    hipMemsetAsync(ws + WS_PERM, 0, 2 * 17408 * 4, stream);
    hipMemsetAsync(d_out, 0, (size_t)out_size * sizeof(float), stream);

    gate_kernel<<<N_TOK / 4, 256, 0, stream>>>(x, gate_w, hdr, load_sum, ids, probs, xb);
    scan_kernel<<<1, 64, 0, stream>>>(hdr, load_sum, out + (size_t)N_TOK * DIM);
    scatter_kernel<<<N_TOK / 256, 256, 0, stream>>>(ids, probs, hdr, perm, wgt);

    if (fast) {
        transpose_cast<<<dim3(FDIM / 64, DIM / 64, 8), 256, 0, stream>>>(w_gate, wg_t, DIM, FDIM);
        transpose_cast<<<dim3(FDIM / 64, DIM / 64, 8), 256, 0, stream>>>(w_up,   wu_t, DIM, FDIM);
        transpose_cast<<<dim3(DIM / 64, FDIM / 64, 8), 256, 0, stream>>>(w_down, wd_t, FDIM, DIM);
        gemm_a<<<dim3((FDIM + NT - 1) / NT, 136), 256, 0, stream>>>(xb, wg_t, wu_t, hdr, perm, Hb);
        gemm_b<<<dim3(DIM / NT, 136), 256, 0, stream>>>(Hb, wd_t, hdr, perm, wgt, out);
    } else {
        gemm_a_f32<<<dim3(FDIM / 64, 272), 256, 0, stream>>>(x, w_gate, w_up, hdr, perm, Hb);
        gemm_b_f32<<<dim3(DIM / 64, 272), 256, 0, stream>>>(Hb, w_down, hdr, perm, wgt, out);
    }
}

// Round 3
// 903.750 us; speedup vs baseline: 1.7340x; 1.0141x over previous
//
#include <hip/hip_runtime.h>
#include <hip/hip_bf16.h>
#include <math.h>

#define N_TOK 8192
#define DIM   1024
#define NEXP  8
#define FDIM  2752
#define BK    32
#define MT    128
#define NT    128

typedef __bf16 v8bf __attribute__((ext_vector_type(8)));
typedef __bf16 v4bf __attribute__((ext_vector_type(4)));
typedef float  v4f  __attribute__((ext_vector_type(4)));

// ws layout (bytes)
#define WS_HDR     0                // int[64]: [0..7]=counts [8..15]=cursor [16..24]=poff (poff[8]=total)
#define WS_LOADSUM 256              // float[8]
#define WS_IDS     512              // int[2*N_TOK]
#define WS_PROBS   66048            // float[2*N_TOK]
#define WS_PERM    131584           // int[17408]
#define WS_WGT     201216           // float[17408]
#define WS_H       270848           // bf16[17408*FDIM] = 95,813,632 B
#define WS_XBF     96084480ull      // bf16[N_TOK*DIM] = 16,777,216 B
#define WS_WG_T    112861696ull     // bf16[8*FDIM*DIM] = 45,088,768 B each
#define WS_WU_T    157950464ull
#define WS_WD_T    203039232ull

__device__ __forceinline__ void gld16(const __bf16* g, __bf16* l) {
    __builtin_amdgcn_global_load_lds(
        (const __attribute__((address_space(1))) void*)g,
        (__attribute__((address_space(3))) void*)l, 16, 0, 0);
}

// ---------------- gating: logits -> softmax -> top2 -> renorm (+ x cast) ----------------
__global__ __launch_bounds__(256) void gate_kernel(
    const float* __restrict__ x, const float* __restrict__ gw,
    int* __restrict__ hdr, float* __restrict__ load_sum,
    int* __restrict__ ids, float* __restrict__ probs, __bf16* __restrict__ xb)
{
    __shared__ float s_load[NEXP];
    __shared__ int   s_cnt[NEXP];
    int tid = threadIdx.x;
    if (tid < NEXP) { s_load[tid] = 0.f; s_cnt[tid] = 0; }
    __syncthreads();

    int wave = tid >> 6, lane = tid & 63;
    int tok = blockIdx.x * 4 + wave;
    float acc[NEXP];
#pragma unroll
    for (int e = 0; e < NEXP; e++) acc[e] = 0.f;
    const float4* xr4 = (const float4*)(x + (size_t)tok * DIM);
#pragma unroll
    for (int it = 0; it < 4; it++) {
        int d4 = it * 64 + lane;
        float4 xv = xr4[d4];
        v4bf vb;
        vb[0] = (__bf16)xv.x; vb[1] = (__bf16)xv.y;
        vb[2] = (__bf16)xv.z; vb[3] = (__bf16)xv.w;
        *(v4bf*)&xb[(size_t)tok * DIM + d4 * 4] = vb;
        int d = d4 * 4;
#pragma unroll
        for (int e = 0; e < NEXP; e++)
            acc[e] += xv.x * gw[d * NEXP + e] + xv.y * gw[(d + 1) * NEXP + e]
                    + xv.z * gw[(d + 2) * NEXP + e] + xv.w * gw[(d + 3) * NEXP + e];
    }
#pragma unroll
    for (int e = 0; e < NEXP; e++) {
#pragma unroll
        for (int off = 32; off > 0; off >>= 1) acc[e] += __shfl_xor(acc[e], off, 64);
    }
    if (lane == 0) {
        float m = acc[0];
#pragma unroll
        for (int e = 1; e < NEXP; e++) m = fmaxf(m, acc[e]);
        float p[NEXP], s = 0.f;
#pragma unroll
        for (int e = 0; e < NEXP; e++) { p[e] = __expf(acc[e] - m); s += p[e]; }
        float inv = 1.f / s;
#pragma unroll
        for (int e = 0; e < NEXP; e++) p[e] *= inv;
        int i1 = 0; float p1 = p[0];
#pragma unroll
        for (int e = 1; e < NEXP; e++) if (p[e] > p1) { p1 = p[e]; i1 = e; }
        int i2 = -1; float p2 = -1.f;
#pragma unroll
        for (int e = 0; e < NEXP; e++) if (e != i1 && p[e] > p2) { p2 = p[e]; i2 = e; }
        float rs = 1.f / (p1 + p2 + 1e-8f);
        ids[tok * 2] = i1;  ids[tok * 2 + 1] = i2;
        probs[tok * 2] = p1 * rs;  probs[tok * 2 + 1] = p2 * rs;
#pragma unroll
        for (int e = 0; e < NEXP; e++) atomicAdd(&s_load[e], p[e]);
        atomicAdd(&s_cnt[i1], 1);  atomicAdd(&s_cnt[i2], 1);
    }
    __syncthreads();
    if (tid < NEXP) {
        atomicAdd(&load_sum[tid], s_load[tid]);
        atomicAdd(&hdr[tid], s_cnt[tid]);
    }
}

// ---------------- scan: 128-aligned segment offsets + aux loss ----------------
__global__ void scan_kernel(int* __restrict__ hdr, const float* __restrict__ load_sum,
                            float* __restrict__ aux_out)
{
    if (threadIdx.x == 0) {
        int off = 0;
        float aux = 0.f;
        for (int e = 0; e < NEXP; e++) {
            hdr[16 + e] = off;
            int c = hdr[e];
            off += (c + 127) & ~127;
            aux += ((float)c / (float)(N_TOK * 2)) * (load_sum[e] / (float)N_TOK);
        }
        hdr[24] = off;
        *aux_out = 0.01f * 8.f * aux;
    }
}

// ---------------- scatter ----------------
__global__ __launch_bounds__(256) void scatter_kernel(
    const int* __restrict__ ids, const float* __restrict__ probs,
    int* __restrict__ hdr, int* __restrict__ perm, float* __restrict__ wgt)
{
    int t = blockIdx.x * 256 + threadIdx.x;
#pragma unroll
    for (int k = 0; k < 2; k++) {
        int e = ids[t * 2 + k];
        int pos = atomicAdd(&hdr[8 + e], 1);
        int slot = hdr[16 + e] + pos;
        perm[slot] = t;
        wgt[slot] = probs[t * 2 + k];
    }
}

// ---------------- transpose+cast body ----------------
__device__ __forceinline__ void tc_body(const float* __restrict__ s, __bf16* __restrict__ d,
                                        int R, int C, int cb, int rb, int tid)
{
    __shared__ float tile[64][65];
    int c = tid & 63;
#pragma unroll
    for (int p = 0; p < 16; p++) {
        int r = p * 4 + (tid >> 6);
        tile[r][c] = s[(size_t)(rb + r) * C + cb + c];
    }
    __syncthreads();
#pragma unroll
    for (int p = 0; p < 2; p++) {
        int cc = p * 32 + (tid >> 3);
        int rr0 = (tid & 7) * 8;
        v8bf v;
#pragma unroll
        for (int j = 0; j < 8; j++) v[j] = (__bf16)tile[rr0 + j][cc];
        *(v8bf*)&d[(size_t)(cb + cc) * R + rb + rr0] = v;
    }
}

// gate+up fused: z = which*8 + e
__global__ __launch_bounds__(256) void transpose_gu(
    const float* __restrict__ wg, const float* __restrict__ wu,
    __bf16* __restrict__ wgt, __bf16* __restrict__ wut)
{
    int which = blockIdx.z >> 3, e = blockIdx.z & 7;
    size_t slab = (size_t)e * DIM * FDIM;
    const float* s = (which ? wu : wg) + slab;
    __bf16* d = (which ? wut : wgt) + slab;
    tc_body(s, d, DIM, FDIM, blockIdx.x * 64, blockIdx.y * 64, threadIdx.x);
}

__global__ __launch_bounds__(256) void transpose_d(
    const float* __restrict__ wd, __bf16* __restrict__ wdt)
{
    size_t slab = (size_t)blockIdx.z * DIM * FDIM;
    tc_body(wd + slab, wdt + slab, FDIM, DIM, blockIdx.x * 64, blockIdx.y * 64, threadIdx.x);
}

// ---------------- pass A: H = silu(X@Wg)*(X@Wu), 128x128, swizzled staging ----------------
__global__ __launch_bounds__(256, 2) void gemm_a(
    const __bf16* __restrict__ xb, const __bf16* __restrict__ wg_t,
    const __bf16* __restrict__ wu_t, const int* __restrict__ hdr,
    const int* __restrict__ perm, __bf16* __restrict__ Hb)
{
    int mbase = blockIdx.y * MT;
    if (mbase >= hdr[24]) return;
    int e = 0;
    while (mbase >= hdr[17 + e]) e++;
    const __bf16* wg = wg_t + (size_t)e * DIM * FDIM;   // [F][K]
    const __bf16* wu = wu_t + (size_t)e * DIM * FDIM;
    int fbase = blockIdx.x * NT;

    __shared__ __align__(16) __bf16 sA[MT * BK];
    __shared__ __align__(16) __bf16 sBg[NT * BK];
    __shared__ __align__(16) __bf16 sBu[NT * BK];

    int tid = threadIdx.x, wave = tid >> 6, lane = tid & 63;
    int srow = wave * 32 + (lane >> 2);
    // swizzle: LDS slot (r, c) holds global chunk c ^ ((r>>1)&3)
    int gk = (((lane & 3) ^ ((lane >> 3) & 3)) * 8);

    int prow0 = perm[mbase + srow];
    int prow1 = perm[mbase + srow + 16];
    const __bf16* ag0 = xb + (size_t)prow0 * DIM + gk;
    const __bf16* ag1 = xb + (size_t)prow1 * DIM + gk;
    const __bf16* bg0 = wg + (size_t)(fbase + srow) * DIM + gk;
    const __bf16* bg1 = wg + (size_t)(fbase + srow + 16) * DIM + gk;
    const __bf16* bu0 = wu + (size_t)(fbase + srow) * DIM + gk;
    const __bf16* bu1 = wu + (size_t)(fbase + srow + 16) * DIM + gk;

    __bf16* lA0 = sA  + (wave * 32) * BK;
    __bf16* lA1 = sA  + (wave * 32 + 16) * BK;
    __bf16* lG0 = sBg + (wave * 32) * BK;
    __bf16* lG1 = sBg + (wave * 32 + 16) * BK;
    __bf16* lU0 = sBu + (wave * 32) * BK;
    __bf16* lU1 = sBu + (wave * 32 + 16) * BK;

    int wm = (wave >> 1) * 64, wn = (wave & 1) * 64;
    int fm = lane & 15;
    int fko = (((lane >> 4) ^ ((fm >> 1) & 3)) * 8);   // swizzled fragment chunk

    v4f accg[4][4], accu[4][4];
#pragma unroll
    for (int i = 0; i < 4; i++)
#pragma unroll
        for (int j = 0; j < 4; j++) {
            accg[i][j] = (v4f){0.f, 0.f, 0.f, 0.f};
            accu[i][j] = (v4f){0.f, 0.f, 0.f, 0.f};
        }

    for (int k0 = 0; k0 < DIM; k0 += BK) {
        gld16(ag0, lA0);  gld16(ag1, lA1);
        gld16(bg0, lG0);  gld16(bg1, lG1);
        gld16(bu0, lU0);  gld16(bu1, lU1);
        ag0 += BK; ag1 += BK; bg0 += BK; bg1 += BK; bu0 += BK; bu1 += BK;
        __syncthreads();

        v8bf af[4], bgf[4], buf_[4];
#pragma unroll
        for (int i = 0; i < 4; i++) af[i] = *(v8bf*)&sA[(wm + i * 16 + fm) * BK + fko];
#pragma unroll
        for (int j = 0; j < 4; j++) {
            bgf[j]  = *(v8bf*)&sBg[(wn + j * 16 + fm) * BK + fko];
            buf_[j] = *(v8bf*)&sBu[(wn + j * 16 + fm) * BK + fko];
        }
#pragma unroll
        for (int i = 0; i < 4; i++)
#pragma unroll
            for (int j = 0; j < 4; j++) {
                accg[i][j] = __builtin_amdgcn_mfma_f32_16x16x32_bf16(af[i], bgf[j],  accg[i][j], 0, 0, 0);
                accu[i][j] = __builtin_amdgcn_mfma_f32_16x16x32_bf16(af[i], buf_[j], accu[i][j], 0, 0, 0);
            }
        __syncthreads();
    }

    int rq = (lane >> 4) * 4;
#pragma unroll
    for (int i = 0; i < 4; i++) {
        int row = mbase + wm + i * 16 + rq;
#pragma unroll
        for (int j = 0; j < 4; j++) {
            int col = fbase + wn + j * 16 + fm;
            if (col < FDIM) {
#pragma unroll
                for (int r = 0; r < 4; r++) {
                    float g = accg[i][j][r], u = accu[i][j][r];
                    float h = g / (1.f + __expf(-g)) * u;
                    Hb[(size_t)(row + r) * FDIM + col] = (__bf16)h;
                }
            }
        }
    }
}

// ---------------- pass B: out += w * (H @ Wd), 128x128, swizzled staging ----------------
__global__ __launch_bounds__(256, 2) void gemm_b(
    const __bf16* __restrict__ Hb, const __bf16* __restrict__ wd_t,
    const int* __restrict__ hdr, const int* __restrict__ perm,
    const float* __restrict__ wgt, float* __restrict__ out)
{
    int mbase = blockIdx.y * MT;
    if (mbase >= hdr[24]) return;
    int e = 0;
    while (mbase >= hdr[17 + e]) e++;
    const __bf16* wd = wd_t + (size_t)e * FDIM * DIM;   // [D][F]
    int nbase = blockIdx.x * NT;

    __shared__ __align__(16) __bf16 sA[MT * BK];
    __shared__ __align__(16) __bf16 sB[NT * BK];

    int tid = threadIdx.x, wave = tid >> 6, lane = tid & 63;
    int srow = wave * 32 + (lane >> 2);
    int gk = (((lane & 3) ^ ((lane >> 3) & 3)) * 8);

    const __bf16* ag0 = Hb + (size_t)(mbase + srow) * FDIM + gk;
    const __bf16* ag1 = Hb + (size_t)(mbase + srow + 16) * FDIM + gk;
    const __bf16* bg0 = wd + (size_t)(nbase + srow) * FDIM + gk;
    const __bf16* bg1 = wd + (size_t)(nbase + srow + 16) * FDIM + gk;

    __bf16* lA0 = sA + (wave * 32) * BK;
    __bf16* lA1 = sA + (wave * 32 + 16) * BK;
    __bf16* lB0 = sB + (wave * 32) * BK;
    __bf16* lB1 = sB + (wave * 32 + 16) * BK;

    int wm = (wave >> 1) * 64, wn = (wave & 1) * 64;
    int fm = lane & 15;
    int fko = (((lane >> 4) ^ ((fm >> 1) & 3)) * 8);

    v4f acc[4][4];
#pragma unroll
    for (int i = 0; i < 4; i++)
#pragma unroll
        for (int j = 0; j < 4; j++) acc[i][j] = (v4f){0.f, 0.f, 0.f, 0.f};

    for (int k0 = 0; k0 < FDIM; k0 += BK) {
        gld16(ag0, lA0);  gld16(ag1, lA1);
        gld16(bg0, lB0);  gld16(bg1, lB1);
        ag0 += BK; ag1 += BK; bg0 += BK; bg1 += BK;
        __syncthreads();

        v8bf af[4], bf_[4];
#pragma unroll
        for (int i = 0; i < 4; i++) af[i]  = *(v8bf*)&sA[(wm + i * 16 + fm) * BK + fko];
#pragma unroll
        for (int j = 0; j < 4; j++) bf_[j] = *(v8bf*)&sB[(wn + j * 16 + fm) * BK + fko];
#pragma unroll
        for (int i = 0; i < 4; i++)
#pragma unroll
            for (int j = 0; j < 4; j++)
                acc[i][j] = __builtin_amdgcn_mfma_f32_16x16x32_bf16(af[i], bf_[j], acc[i][j], 0, 0, 0);
        __syncthreads();
    }

    int rq = (lane >> 4) * 4;
#pragma unroll
    for (int i = 0; i < 4; i++) {
#pragma unroll
        for (int r = 0; r < 4; r++) {
            int row = mbase + wm + i * 16 + rq + r;
            int tok = perm[row];
            float w = wgt[row];
            size_t ob = (size_t)tok * DIM + nbase + wn + fm;
#pragma unroll
            for (int j = 0; j < 4; j++)
                atomicAdd(&out[ob + j * 16], acc[i][j][r] * w);
        }
    }
}

extern "C" void kernel_launch(void* const* d_in, const int* in_sizes, int n_in,
                              void* d_out, int out_size, void* d_ws, size_t ws_size,
                              hipStream_t stream)
{
    const float* x      = (const float*)d_in[0];
    const float* gate_w = (const float*)d_in[1];
    const float* w_gate = (const float*)d_in[2];
    const float* w_up   = (const float*)d_in[3];
    const float* w_down = (const float*)d_in[4];
    float* out = (float*)d_out;

    char* ws = (char*)d_ws;
    int*   hdr      = (int*)(ws + WS_HDR);
    float* load_sum = (float*)(ws + WS_LOADSUM);
    int*   ids      = (int*)(ws + WS_IDS);
    float* probs    = (float*)(ws + WS_PROBS);
    int*   perm     = (int*)(ws + WS_PERM);
    float* wgt      = (float*)(ws + WS_WGT);
    __bf16* Hb      = (__bf16*)(ws + WS_H);
    __bf16* xb      = (__bf16*)(ws + WS_XBF);
    __bf16* wg_t    = (__bf16*)(ws + WS_WG_T);
    __bf16* wu_t    = (__bf16*)(ws + WS_WU_T);
    __bf16* wd_t    = (__bf16*)(ws + WS_WD_T);

    hipMemsetAsync(ws, 0, 512, stream);
    hipMemsetAsync(ws + WS_PERM, 0, 2 * 17408 * 4, stream);
    hipMemsetAsync(d_out, 0, (size_t)out_size * sizeof(float), stream);

    gate_kernel<<<N_TOK / 4, 256, 0, stream>>>(x, gate_w, hdr, load_sum, ids, probs, xb);
    scan_kernel<<<1, 64, 0, stream>>>(hdr, load_sum, out + (size_t)N_TOK * DIM);
    scatter_kernel<<<N_TOK / 256, 256, 0, stream>>>(ids, probs, hdr, perm, wgt);

    transpose_gu<<<dim3(FDIM / 64, DIM / 64, 16), 256, 0, stream>>>(w_gate, w_up, wg_t, wu_t);
    transpose_d<<<dim3(DIM / 64, FDIM / 64, 8), 256, 0, stream>>>(w_down, wd_t);

    gemm_a<<<dim3((FDIM + NT - 1) / NT, 136), 256, 0, stream>>>(xb, wg_t, wu_t, hdr, perm, Hb);
    gemm_b<<<dim3(DIM / NT, 136), 256, 0, stream>>>(Hb, wd_t, hdr, perm, wgt, out);
}

// Round 4
// 805.794 us; speedup vs baseline: 1.9448x; 1.1216x over previous
//
#include <hip/hip_runtime.h>
#include <hip/hip_bf16.h>
#include <math.h>

#define N_TOK 8192
#define DIM   1024
#define NEXP  8
#define FDIM  2752
#define BK    64
#define MT    128
#define NT    128

typedef __bf16 v8bf __attribute__((ext_vector_type(8)));
typedef __bf16 v4bf __attribute__((ext_vector_type(4)));
typedef float  v4f  __attribute__((ext_vector_type(4)));

// ws layout (bytes)
#define WS_HDR     0                // int[64]: [0..7]=counts [8..15]=cursor [16..24]=poff (poff[8]=total)
#define WS_LOADSUM 256              // float[8]
#define WS_IDS     512              // int[2*N_TOK]  (after scatter: holds SLOT per (tok,k))
#define WS_PROBS   66048            // float[2*N_TOK]
#define WS_PERM    131584           // int[17408]
#define WS_WGT     201216           // float[17408]
#define WS_H       270848           // bf16[17408*FDIM] = 95,813,632 B
#define WS_XBF     96084480ull      // bf16[N_TOK*DIM]
#define WS_WG_T    112861696ull     // bf16[8*FDIM*DIM] = 45,088,768 B each
#define WS_WU_T    157950464ull
#define WS_WD_T    203039232ull
#define WS_Y       112861696ull     // fp32[17408*1024] = 71,303,168 B, overlays wg_t/wu_t (dead after gemm_a)

__device__ __forceinline__ void gld16(const __bf16* g, __bf16* l) {
    __builtin_amdgcn_global_load_lds(
        (const __attribute__((address_space(1))) void*)g,
        (__attribute__((address_space(3))) void*)l, 16, 0, 0);
}

// ---------------- gating ----------------
__global__ __launch_bounds__(256) void gate_kernel(
    const float* __restrict__ x, const float* __restrict__ gw,
    int* __restrict__ hdr, float* __restrict__ load_sum,
    int* __restrict__ ids, float* __restrict__ probs, __bf16* __restrict__ xb)
{
    __shared__ float s_load[NEXP];
    __shared__ int   s_cnt[NEXP];
    int tid = threadIdx.x;
    if (tid < NEXP) { s_load[tid] = 0.f; s_cnt[tid] = 0; }
    __syncthreads();

    int wave = tid >> 6, lane = tid & 63;
    int tok = blockIdx.x * 4 + wave;
    float acc[NEXP];
#pragma unroll
    for (int e = 0; e < NEXP; e++) acc[e] = 0.f;
    const float4* xr4 = (const float4*)(x + (size_t)tok * DIM);
#pragma unroll
    for (int it = 0; it < 4; it++) {
        int d4 = it * 64 + lane;
        float4 xv = xr4[d4];
        v4bf vb;
        vb[0] = (__bf16)xv.x; vb[1] = (__bf16)xv.y;
        vb[2] = (__bf16)xv.z; vb[3] = (__bf16)xv.w;
        *(v4bf*)&xb[(size_t)tok * DIM + d4 * 4] = vb;
        int d = d4 * 4;
#pragma unroll
        for (int e = 0; e < NEXP; e++)
            acc[e] += xv.x * gw[d * NEXP + e] + xv.y * gw[(d + 1) * NEXP + e]
                    + xv.z * gw[(d + 2) * NEXP + e] + xv.w * gw[(d + 3) * NEXP + e];
    }
#pragma unroll
    for (int e = 0; e < NEXP; e++) {
#pragma unroll
        for (int off = 32; off > 0; off >>= 1) acc[e] += __shfl_xor(acc[e], off, 64);
    }
    if (lane == 0) {
        float m = acc[0];
#pragma unroll
        for (int e = 1; e < NEXP; e++) m = fmaxf(m, acc[e]);
        float p[NEXP], s = 0.f;
#pragma unroll
        for (int e = 0; e < NEXP; e++) { p[e] = __expf(acc[e] - m); s += p[e]; }
        float inv = 1.f / s;
#pragma unroll
        for (int e = 0; e < NEXP; e++) p[e] *= inv;
        int i1 = 0; float p1 = p[0];
#pragma unroll
        for (int e = 1; e < NEXP; e++) if (p[e] > p1) { p1 = p[e]; i1 = e; }
        int i2 = -1; float p2 = -1.f;
#pragma unroll
        for (int e = 0; e < NEXP; e++) if (e != i1 && p[e] > p2) { p2 = p[e]; i2 = e; }
        float rs = 1.f / (p1 + p2 + 1e-8f);
        ids[tok * 2] = i1;  ids[tok * 2 + 1] = i2;
        probs[tok * 2] = p1 * rs;  probs[tok * 2 + 1] = p2 * rs;
#pragma unroll
        for (int e = 0; e < NEXP; e++) atomicAdd(&s_load[e], p[e]);
        atomicAdd(&s_cnt[i1], 1);  atomicAdd(&s_cnt[i2], 1);
    }
    __syncthreads();
    if (tid < NEXP) {
        atomicAdd(&load_sum[tid], s_load[tid]);
        atomicAdd(&hdr[tid], s_cnt[tid]);
    }
}

// ---------------- scan ----------------
__global__ void scan_kernel(int* __restrict__ hdr, const float* __restrict__ load_sum,
                            float* __restrict__ aux_out)
{
    if (threadIdx.x == 0) {
        int off = 0;
        float aux = 0.f;
        for (int e = 0; e < NEXP; e++) {
            hdr[16 + e] = off;
            int c = hdr[e];
            off += (c + 127) & ~127;
            aux += ((float)c / (float)(N_TOK * 2)) * (load_sum[e] / (float)N_TOK);
        }
        hdr[24] = off;
        *aux_out = 0.01f * 8.f * aux;
    }
}

// ---------------- scatter: build lists; store slot back into ids ----------------
__global__ __launch_bounds__(256) void scatter_kernel(
    const int* __restrict__ probs_dummy, const float* __restrict__ probs,
    int* __restrict__ hdr, int* __restrict__ perm, float* __restrict__ wgt,
    int* __restrict__ ids)
{
    int t = blockIdx.x * 256 + threadIdx.x;
#pragma unroll
    for (int k = 0; k < 2; k++) {
        int e = ids[t * 2 + k];
        int pos = atomicAdd(&hdr[8 + e], 1);
        int slot = hdr[16 + e] + pos;
        perm[slot] = t;
        wgt[slot] = probs[t * 2 + k];
        ids[t * 2 + k] = slot;          // in-place: token -> slot map for combine
    }
}

// ---------------- transpose+cast: [R][C] f32 -> [C][R] bf16 ----------------
__device__ __forceinline__ void tc_body(const float* __restrict__ s, __bf16* __restrict__ d,
                                        int R, int C, int cb, int rb, int tid)
{
    __shared__ float tile[64][65];
    int c4 = (tid & 15) * 4, rr = tid >> 4;
#pragma unroll
    for (int p = 0; p < 4; p++) {
        int r = p * 16 + rr;
        float4 v = *(const float4*)&s[(size_t)(rb + r) * C + cb + c4];
        tile[r][c4] = v.x; tile[r][c4 + 1] = v.y; tile[r][c4 + 2] = v.z; tile[r][c4 + 3] = v.w;
    }
    __syncthreads();
#pragma unroll
    for (int p = 0; p < 2; p++) {
        int cc = p * 32 + (tid >> 3);
        int rr0 = (tid & 7) * 8;
        v8bf v;
#pragma unroll
        for (int j = 0; j < 8; j++) v[j] = (__bf16)tile[rr0 + j][cc];
        *(v8bf*)&d[(size_t)(cb + cc) * R + rb + rr0] = v;
    }
}

__global__ __launch_bounds__(256) void transpose_gu(
    const float* __restrict__ wg, const float* __restrict__ wu,
    __bf16* __restrict__ wgt, __bf16* __restrict__ wut)
{
    int which = blockIdx.z >> 3, e = blockIdx.z & 7;
    size_t slab = (size_t)e * DIM * FDIM;
    const float* s = (which ? wu : wg) + slab;
    __bf16* d = (which ? wut : wgt) + slab;
    tc_body(s, d, DIM, FDIM, blockIdx.x * 64, blockIdx.y * 64, threadIdx.x);
}

__global__ __launch_bounds__(256) void transpose_d(
    const float* __restrict__ wd, __bf16* __restrict__ wdt)
{
    size_t slab = (size_t)blockIdx.z * DIM * FDIM;
    tc_body(wd + slab, wdt + slab, FDIM, DIM, blockIdx.x * 64, blockIdx.y * 64, threadIdx.x);
}

// ---------------- pass A: H = silu(X@Wg)*(X@Wu), 128x128, BK=64 ----------------
__global__ __launch_bounds__(256, 2) void gemm_a(
    const __bf16* __restrict__ xb, const __bf16* __restrict__ wg_t,
    const __bf16* __restrict__ wu_t, const int* __restrict__ hdr,
    const int* __restrict__ perm, __bf16* __restrict__ Hb)
{
    int mbase = blockIdx.y * MT;
    if (mbase >= hdr[24]) return;
    int e = 0;
    while (mbase >= hdr[17 + e]) e++;
    const __bf16* wg = wg_t + (size_t)e * DIM * FDIM;   // [F][K]
    const __bf16* wu = wu_t + (size_t)e * DIM * FDIM;
    int fbase = blockIdx.x * NT;

    __shared__ __align__(16) __bf16 sA[MT * BK];
    __shared__ __align__(16) __bf16 sBg[NT * BK];
    __shared__ __align__(16) __bf16 sBu[NT * BK];

    int tid = threadIdx.x, wave = tid >> 6, lane = tid & 63;
    int rsub = lane >> 3;                      // row-within-issue 0..7
    int gch  = (lane & 7) ^ rsub;              // global chunk (swizzled)

    const __bf16 *agp[4], *bgp[4], *bup[4];
    __bf16 *ldA[4], *ldG[4], *ldU[4];
#pragma unroll
    for (int i = 0; i < 4; i++) {
        int row = wave * 32 + i * 8 + rsub;
        int pr = perm[mbase + row];
        agp[i] = xb + (size_t)pr * DIM + gch * 8;
        bgp[i] = wg + (size_t)(fbase + row) * DIM + gch * 8;
        bup[i] = wu + (size_t)(fbase + row) * DIM + gch * 8;
        ldA[i] = sA  + (wave * 32 + i * 8) * BK;
        ldG[i] = sBg + (wave * 32 + i * 8) * BK;
        ldU[i] = sBu + (wave * 32 + i * 8) * BK;
    }

    int wm = (wave >> 1) * 64, wn = (wave & 1) * 64;
    int fm = lane & 15, kq = lane >> 4;

    v4f accg[4][4], accu[4][4];
#pragma unroll
    for (int i = 0; i < 4; i++)
#pragma unroll
        for (int j = 0; j < 4; j++) {
            accg[i][j] = (v4f){0.f, 0.f, 0.f, 0.f};
            accu[i][j] = (v4f){0.f, 0.f, 0.f, 0.f};
        }

    for (int k0 = 0; k0 < DIM; k0 += BK) {
#pragma unroll
        for (int i = 0; i < 4; i++) {
            gld16(agp[i], ldA[i]);
            gld16(bgp[i], ldG[i]);
            gld16(bup[i], ldU[i]);
            agp[i] += BK; bgp[i] += BK; bup[i] += BK;
        }
        __syncthreads();

#pragma unroll
        for (int h = 0; h < 2; h++) {
            v8bf af[4], bgf[4], buf_[4];
#pragma unroll
            for (int i = 0; i < 4; i++) {
                int row = wm + i * 16 + fm;
                af[i] = *(v8bf*)&sA[row * BK + (((kq + 4 * h) ^ (fm & 7)) * 8)];
            }
#pragma unroll
            for (int j = 0; j < 4; j++) {
                int row = wn + j * 16 + fm;
                int p = ((kq + 4 * h) ^ (fm & 7)) * 8;
                bgf[j]  = *(v8bf*)&sBg[row * BK + p];
                buf_[j] = *(v8bf*)&sBu[row * BK + p];
            }
#pragma unroll
            for (int i = 0; i < 4; i++)
#pragma unroll
                for (int j = 0; j < 4; j++) {
                    accg[i][j] = __builtin_amdgcn_mfma_f32_16x16x32_bf16(af[i], bgf[j],  accg[i][j], 0, 0, 0);
                    accu[i][j] = __builtin_amdgcn_mfma_f32_16x16x32_bf16(af[i], buf_[j], accu[i][j], 0, 0, 0);
                }
        }
        __syncthreads();
    }

    int rq = kq * 4;
#pragma unroll
    for (int i = 0; i < 4; i++) {
        int row = mbase + wm + i * 16 + rq;
#pragma unroll
        for (int j = 0; j < 4; j++) {
            int col = fbase + wn + j * 16 + fm;
            if (col < FDIM) {
#pragma unroll
                for (int r = 0; r < 4; r++) {
                    float g = accg[i][j][r], u = accu[i][j][r];
                    float h = g / (1.f + __expf(-g)) * u;
                    Hb[(size_t)(row + r) * FDIM + col] = (__bf16)h;
                }
            }
        }
    }
}

// ---------------- pass B: Y = H @ Wd (plain stores, no atomics) ----------------
__global__ __launch_bounds__(256, 2) void gemm_b(
    const __bf16* __restrict__ Hb, const __bf16* __restrict__ wd_t,
    const int* __restrict__ hdr, float* __restrict__ Y)
{
    int mbase = blockIdx.y * MT;
    if (mbase >= hdr[24]) return;
    const __bf16* wd = wd_t;                    // expert offset below
    int e = 0;
    while (mbase >= hdr[17 + e]) e++;
    wd += (size_t)e * FDIM * DIM;               // [D][F]
    int nbase = blockIdx.x * NT;

    __shared__ __align__(16) __bf16 sA[MT * BK];
    __shared__ __align__(16) __bf16 sB[NT * BK];

    int tid = threadIdx.x, wave = tid >> 6, lane = tid & 63;
    int rsub = lane >> 3;
    int gch  = (lane & 7) ^ rsub;

    const __bf16 *agp[4], *bgp[4];
    __bf16 *ldA[4], *ldB[4];
#pragma unroll
    for (int i = 0; i < 4; i++) {
        int row = wave * 32 + i * 8 + rsub;
        agp[i] = Hb + (size_t)(mbase + row) * FDIM + gch * 8;
        bgp[i] = wd + (size_t)(nbase + row) * FDIM + gch * 8;
        ldA[i] = sA + (wave * 32 + i * 8) * BK;
        ldB[i] = sB + (wave * 32 + i * 8) * BK;
    }

    int wm = (wave >> 1) * 64, wn = (wave & 1) * 64;
    int fm = lane & 15, kq = lane >> 4;

    v4f acc[4][4];
#pragma unroll
    for (int i = 0; i < 4; i++)
#pragma unroll
        for (int j = 0; j < 4; j++) acc[i][j] = (v4f){0.f, 0.f, 0.f, 0.f};

    for (int k0 = 0; k0 < FDIM; k0 += BK) {
#pragma unroll
        for (int i = 0; i < 4; i++) {
            gld16(agp[i], ldA[i]);
            gld16(bgp[i], ldB[i]);
            agp[i] += BK; bgp[i] += BK;
        }
        __syncthreads();

#pragma unroll
        for (int h = 0; h < 2; h++) {
            v8bf af[4], bf_[4];
#pragma unroll
            for (int i = 0; i < 4; i++) {
                int row = wm + i * 16 + fm;
                af[i] = *(v8bf*)&sA[row * BK + (((kq + 4 * h) ^ (fm & 7)) * 8)];
            }
#pragma unroll
            for (int j = 0; j < 4; j++) {
                int row = wn + j * 16 + fm;
                bf_[j] = *(v8bf*)&sB[row * BK + (((kq + 4 * h) ^ (fm & 7)) * 8)];
            }
#pragma unroll
            for (int i = 0; i < 4; i++)
#pragma unroll
                for (int j = 0; j < 4; j++)
                    acc[i][j] = __builtin_amdgcn_mfma_f32_16x16x32_bf16(af[i], bf_[j], acc[i][j], 0, 0, 0);
        }
        __syncthreads();
    }

    int rq = kq * 4;
#pragma unroll
    for (int i = 0; i < 4; i++) {
#pragma unroll
        for (int r = 0; r < 4; r++) {
            int row = mbase + wm + i * 16 + rq + r;
            size_t yb = (size_t)row * DIM + nbase + wn + fm;
#pragma unroll
            for (int j = 0; j < 4; j++)
                Y[yb + j * 16] = acc[i][j][r];
        }
    }
}

// ---------------- combine: out[t] = w0*Y[s0] + w1*Y[s1] ----------------
__global__ __launch_bounds__(256) void combine_kernel(
    const float* __restrict__ Y, const int* __restrict__ slots,
    const float* __restrict__ wgt, float* __restrict__ out)
{
    int t = blockIdx.x;
    int d = threadIdx.x * 4;
    int s0 = slots[t * 2], s1 = slots[t * 2 + 1];
    float w0 = wgt[s0], w1 = wgt[s1];
    float4 y0 = *(const float4*)&Y[(size_t)s0 * DIM + d];
    float4 y1 = *(const float4*)&Y[(size_t)s1 * DIM + d];
    float4 o;
    o.x = w0 * y0.x + w1 * y1.x;
    o.y = w0 * y0.y + w1 * y1.y;
    o.z = w0 * y0.z + w1 * y1.z;
    o.w = w0 * y0.w + w1 * y1.w;
    *(float4*)&out[(size_t)t * DIM + d] = o;
}

extern "C" void kernel_launch(void* const* d_in, const int* in_sizes, int n_in,
                              void* d_out, int out_size, void* d_ws, size_t ws_size,
                              hipStream_t stream)
{
    const float* x      = (const float*)d_in[0];
    const float* gate_w = (const float*)d_in[1];
    const float* w_gate = (const float*)d_in[2];
    const float* w_up   = (const float*)d_in[3];
    const float* w_down = (const float*)d_in[4];
    float* out = (float*)d_out;

    char* ws = (char*)d_ws;
    int*   hdr      = (int*)(ws + WS_HDR);
    float* load_sum = (float*)(ws + WS_LOADSUM);
    int*   ids      = (int*)(ws + WS_IDS);
    float* probs    = (float*)(ws + WS_PROBS);
    int*   perm     = (int*)(ws + WS_PERM);
    float* wgt      = (float*)(ws + WS_WGT);
    __bf16* Hb      = (__bf16*)(ws + WS_H);
    __bf16* xb      = (__bf16*)(ws + WS_XBF);
    __bf16* wg_t    = (__bf16*)(ws + WS_WG_T);
    __bf16* wu_t    = (__bf16*)(ws + WS_WU_T);
    __bf16* wd_t    = (__bf16*)(ws + WS_WD_T);
    float*  Y       = (float*)(ws + WS_Y);

    hipMemsetAsync(ws, 0, 512, stream);
    hipMemsetAsync(ws + WS_PERM, 0, 2 * 17408 * 4, stream);

    gate_kernel<<<N_TOK / 4, 256, 0, stream>>>(x, gate_w, hdr, load_sum, ids, probs, xb);
    scan_kernel<<<1, 64, 0, stream>>>(hdr, load_sum, out + (size_t)N_TOK * DIM);
    scatter_kernel<<<N_TOK / 256, 256, 0, stream>>>(nullptr, probs, hdr, perm, wgt, ids);

    transpose_gu<<<dim3(FDIM / 64, DIM / 64, 16), 256, 0, stream>>>(w_gate, w_up, wg_t, wu_t);
    transpose_d<<<dim3(DIM / 64, FDIM / 64, 8), 256, 0, stream>>>(w_down, wd_t);

    gemm_a<<<dim3((FDIM + NT - 1) / NT, 136), 256, 0, stream>>>(xb, wg_t, wu_t, hdr, perm, Hb);
    gemm_b<<<dim3(DIM / NT, 136), 256, 0, stream>>>(Hb, wd_t, hdr, Y);
    combine_kernel<<<N_TOK, 256, 0, stream>>>(Y, ids, wgt, out);
}